// Round 1
// 154.534 us; speedup vs baseline: 1.0180x; 1.0180x over previous
//
#include <hip/hip_runtime.h>

// Fused CRF NLL: B=1024, T=2048, K=9 (START=7, STOP=8).
// One block per sentence (256 thr = 32 chunk-groups x 8 lanes).
// Phase 1: gold score, data-parallel, unrolled-8 loads.
// Phase 2: per-chunk 7x7 linear-space transfer matrix, 1 lane per column.
//   - DYNAMIC chunk length Lb = ceil((len-1)/32): all chunks active, critical
//     path ~len/32 steps instead of fixed 64.
//   - E in SGPRs (readfirstlane)
//   - lane l loads ONLY f[t][l] (1 dword/step), exp once, shares via ds_bpermute
//   - ef broadcasts for a 4-step group issued BEFORE the 4 FMA blocks, so the
//     ds_bpermute round-trip is off the recurrence critical path.
//   - renorm every 4 steps (growth bounded ~1e17, fp32-safe)
// Phase 3: threads 0..7, REPLICATED alpha (all 7 values per lane):
//   in-lane lse per row -> redistribute via 7 shfl -> in-lane recenter
//   (no cross-lane max tree), next-row LDS prefetch, STOP readout,
//   atomicAdd((fwd-gold)/B).

#define START_TAG 7
#define STOP_TAG  8
#define KDIM      9
#define NS        7
#define CHUNKS    32
#define NEGINF    (-1e30f)

__device__ __forceinline__ float rfl(float x) {
    return __int_as_float(__builtin_amdgcn_readfirstlane(__float_as_int(x)));
}

__global__ __launch_bounds__(256) void crf_fused_kernel(
    const float* __restrict__ feats,
    const float* __restrict__ trans,
    const int*   __restrict__ tags,
    const int*   __restrict__ lengths,
    float* __restrict__ out,
    int B, int T)
{
    __shared__ float s_trans[81];
    __shared__ float s_E[49];
    __shared__ float s_M[CHUNKS * 64];   // [c][j*8 + i] rows padded to 8
    __shared__ float s_gold[4];

    const int tid = threadIdx.x;
    const int b   = blockIdx.x;

    if (tid < 81) s_trans[tid] = trans[tid];
    if (tid >= 128 && tid < 177) {
        int k = tid - 128;
        s_E[k] = __expf(trans[(k / 7) * 9 + (k % 7)]);
    }
    __syncthreads();

    const int    len   = lengths[b];
    const int*   tg    = tags  + (size_t)b * T;
    const float* fbase = feats + (size_t)b * T * KDIM;
    // dynamic chunk length over timesteps [1, len)
    const int    Lb    = (len > 1) ? ((len - 1 + CHUNKS - 1) / CHUNKS) : 1;

    // ---------------- phase 1: gold score ----------------
    {
        int per = (T >> 8) > 0 ? (T >> 8) : 1;
        int t0  = tid * per;
        float g = 0.f;
        if (t0 < len) {
            int te   = min(t0 + per, len);
            int prev = (t0 == 0) ? START_TAG : tg[t0 - 1];
            if (per == 8) {
                #pragma unroll
                for (int k = 0; k < 8; ++k) {
                    int t   = t0 + k;
                    int tc  = min(t, te - 1);
                    int cur = tg[tc];
                    float v = s_trans[cur * 9 + prev] + fbase[(size_t)tc * KDIM + cur];
                    g += (t < te) ? v : 0.f;
                    prev = cur;
                }
            } else {
                for (int k = 0; k < per; ++k) {
                    int t   = t0 + k;
                    int tc  = min(t, te - 1);
                    int cur = tg[tc];
                    float v = s_trans[cur * 9 + prev] + fbase[(size_t)tc * KDIM + cur];
                    g += (t < te) ? v : 0.f;
                    prev = cur;
                }
            }
            if (len - 1 >= t0 && len - 1 < t0 + per)
                g += s_trans[STOP_TAG * 9 + tg[len - 1]];
        }
        #pragma unroll
        for (int off = 32; off > 0; off >>= 1) g += __shfl_xor(g, off, 64);
        if ((tid & 63) == 0) s_gold[tid >> 6] = g;
    }

    // ---------------- phase 2: chunk matrices ----------------
    {
        const int lane8  = tid & 7;
        const int c      = tid >> 3;
        const int tstart = 1 + c * Lb;
        const int tend   = min(tstart + Lb, len);

        if (lane8 < NS) {
            float* Mw = s_M + c * 64;
            if (tstart < tend) {
                float E[49];
                #pragma unroll
                for (int k = 0; k < 49; ++k) E[k] = rfl(s_E[k]);

                // precomputed bpermute byte addresses for lanes (group base | j)
                int baddr[NS];
                #pragma unroll
                for (int j = 0; j < NS; ++j) baddr[j] = (((tid & 56) | j) << 2);

                float p[NS];
                #pragma unroll
                for (int j = 0; j < NS; ++j) p[j] = (j == lane8) ? 1.f : 0.f;
                float s = 0.f;
                int rem = tend - tstart;

                const float* fp = fbase + (size_t)tstart * KDIM + lane8;

                #define CRF_MAT(EF) do {                                        \
                    float q[NS];                                                \
                    _Pragma("unroll")                                           \
                    for (int j = 0; j < NS; ++j) {                              \
                        float acc = E[j * 7] * p[0];                            \
                        _Pragma("unroll")                                       \
                        for (int i = 1; i < NS; ++i)                            \
                            acc = fmaf(E[j * 7 + i], p[i], acc);                \
                        q[j] = acc;                                             \
                    }                                                           \
                    _Pragma("unroll")                                           \
                    for (int j = 0; j < NS; ++j) p[j] = q[j] * EF[j];           \
                } while (0)

                #define CRF_BCAST(DST, XF) do {                                 \
                    float _e = __expf(XF);                                      \
                    _Pragma("unroll")                                           \
                    for (int j = 0; j < NS; ++j)                                \
                        DST[j] = __int_as_float(                                \
                            __builtin_amdgcn_ds_bpermute(                       \
                                baddr[j], __float_as_int(_e)));                 \
                } while (0)

                #define CRF_STEP(XF) do {                                       \
                    float _ef[NS];                                              \
                    CRF_BCAST(_ef, XF);                                         \
                    CRF_MAT(_ef);                                               \
                } while (0)

                #define CRF_RENORM() do {                                       \
                    float m = p[0];                                             \
                    _Pragma("unroll")                                           \
                    for (int j = 1; j < NS; ++j) m = fmaxf(m, p[j]);            \
                    float rm = __builtin_amdgcn_rcpf(m);                        \
                    _Pragma("unroll")                                           \
                    for (int j = 0; j < NS; ++j) p[j] *= rm;                    \
                    s += __logf(m);                                             \
                } while (0)

                // initial preload (clamped so short chunks never read OOB)
                int o1 = KDIM * min(1, rem - 1);
                int o2 = KDIM * min(2, rem - 1);
                int o3 = KDIM * min(3, rem - 1);
                float x0 = fp[0], x1 = fp[o1], x2 = fp[o2], x3 = fp[o3];
                fp += 4 * KDIM;

                while (rem >= 8) {
                    float y0 = fp[0], y1 = fp[KDIM], y2 = fp[2 * KDIM], y3 = fp[3 * KDIM];
                    fp += 4 * KDIM;
                    // issue all 28 ef broadcasts up front: DS latency overlaps
                    // the ~450 cycles of FMA issue below.
                    float efA[NS], efB[NS], efC[NS], efD[NS];
                    CRF_BCAST(efA, x0);
                    CRF_BCAST(efB, x1);
                    CRF_BCAST(efC, x2);
                    CRF_BCAST(efD, x3);
                    CRF_MAT(efA); CRF_MAT(efB); CRF_MAT(efC); CRF_MAT(efD);
                    CRF_RENORM();
                    x0 = y0; x1 = y1; x2 = y2; x3 = y3;
                    rem -= 4;
                }
                if (rem > 4) {
                    int e1 = KDIM * min(1, rem - 5);
                    int e2 = KDIM * min(2, rem - 5);
                    float y0 = fp[0], y1 = fp[e1], y2 = fp[e2];
                    float efA[NS], efB[NS], efC[NS], efD[NS];
                    CRF_BCAST(efA, x0);
                    CRF_BCAST(efB, x1);
                    CRF_BCAST(efC, x2);
                    CRF_BCAST(efD, x3);
                    CRF_MAT(efA); CRF_MAT(efB); CRF_MAT(efC); CRF_MAT(efD);
                    CRF_RENORM();
                    x0 = y0; x1 = y1; x2 = y2;
                    rem -= 4;
                }
                // rem in [1,4]
                CRF_STEP(x0);
                if (rem > 1) CRF_STEP(x1);
                if (rem > 2) CRF_STEP(x2);
                if (rem > 3) CRF_STEP(x3);

                #pragma unroll
                for (int j = 0; j < NS; ++j)
                    Mw[j * 8 + lane8] = __logf(p[j]) + s;

                #undef CRF_MAT
                #undef CRF_BCAST
                #undef CRF_STEP
                #undef CRF_RENORM
            } else {
                #pragma unroll
                for (int j = 0; j < NS; ++j)
                    Mw[j * 8 + lane8] = (j == lane8) ? 0.f : NEGINF;
            }
        }
    }
    __syncthreads();

    // ---------------- phase 3: replicated-alpha fold + output ----------------
    if (tid < 8) {
        const int  lane  = tid;
        const bool isrow = (lane < NS);
        const int  row   = isrow ? lane : 0;

        // every lane holds the full alpha vector (t=0 emission applied)
        float a[NS];
        #pragma unroll
        for (int i = 0; i < NS; ++i)
            a[i] = s_trans[i * 9 + START_TAG] + fbase[i];
        float S;
        {
            float mm = fmaxf(fmaxf(fmaxf(a[0], a[1]), fmaxf(a[2], a[3])),
                             fmaxf(fmaxf(a[4], a[5]), a[6]));
            S = mm;
            #pragma unroll
            for (int i = 0; i < NS; ++i) a[i] -= mm;
        }

        int nc = (len > 1) ? ((len - 1 + Lb - 1) / Lb) : 0;
        if (nc > CHUNKS) nc = CHUNKS;

        const float* Mr0 = s_M + row * 8;
        float4 mA = *(const float4*)(Mr0);
        float4 mB = *(const float4*)(Mr0 + 4);
        for (int cc = 0; cc < nc; ++cc) {
            int cn = min(cc + 1, CHUNKS - 1);
            float4 nA = *(const float4*)(Mr0 + cn * 64);
            float4 nB = *(const float4*)(Mr0 + cn * 64 + 4);
            // lane computes lse over its OWN row entirely in-lane
            float t0 = mA.x + a[0], t1 = mA.y + a[1], t2 = mA.z + a[2];
            float t3 = mA.w + a[3], t4 = mB.x + a[4], t5 = mB.y + a[5];
            float t6 = mB.z + a[6];
            float tm = fmaxf(fmaxf(fmaxf(t0, t1), fmaxf(t2, t3)),
                             fmaxf(fmaxf(t4, t5), t6));
            float e0 = __expf(t0 - tm), e1 = __expf(t1 - tm), e2 = __expf(t2 - tm);
            float e3 = __expf(t3 - tm), e4 = __expf(t4 - tm), e5 = __expf(t5 - tm);
            float e6 = __expf(t6 - tm);
            float sum = ((e0 + e1) + (e2 + e3)) + ((e4 + e5) + e6);
            float na = tm + __logf(sum);
            // redistribute new alpha to all lanes, then recenter IN-LANE
            float b0 = __shfl(na, 0, 8), b1 = __shfl(na, 1, 8), b2 = __shfl(na, 2, 8);
            float b3 = __shfl(na, 3, 8), b4 = __shfl(na, 4, 8), b5 = __shfl(na, 5, 8);
            float b6 = __shfl(na, 6, 8);
            float mm = fmaxf(fmaxf(fmaxf(b0, b1), fmaxf(b2, b3)),
                             fmaxf(fmaxf(b4, b5), b6));
            a[0] = b0 - mm; a[1] = b1 - mm; a[2] = b2 - mm;
            a[3] = b3 - mm; a[4] = b4 - mm; a[5] = b5 - mm;
            a[6] = b6 - mm;
            S += mm;
            mA = nA; mB = nB;
        }

        if (lane == 0) {
            float t0 = a[0] + s_trans[STOP_TAG * 9 + 0];
            float t1 = a[1] + s_trans[STOP_TAG * 9 + 1];
            float t2 = a[2] + s_trans[STOP_TAG * 9 + 2];
            float t3 = a[3] + s_trans[STOP_TAG * 9 + 3];
            float t4 = a[4] + s_trans[STOP_TAG * 9 + 4];
            float t5 = a[5] + s_trans[STOP_TAG * 9 + 5];
            float t6 = a[6] + s_trans[STOP_TAG * 9 + 6];
            float tm = fmaxf(fmaxf(fmaxf(t0, t1), fmaxf(t2, t3)),
                             fmaxf(fmaxf(t4, t5), t6));
            float sum = ((__expf(t0 - tm) + __expf(t1 - tm)) +
                         (__expf(t2 - tm) + __expf(t3 - tm))) +
                        ((__expf(t4 - tm) + __expf(t5 - tm)) + __expf(t6 - tm));
            float fwd = S + tm + __logf(sum);
            float g = s_gold[0] + s_gold[1] + s_gold[2] + s_gold[3];
            atomicAdd(out, (fwd - g) * (1.0f / (float)B));
        }
    }
}

__global__ void init_out_kernel(float* out) {
    if (threadIdx.x == 0) out[0] = 0.f;
}

extern "C" void kernel_launch(void* const* d_in, const int* in_sizes, int n_in,
                              void* d_out, int out_size, void* d_ws, size_t ws_size,
                              hipStream_t stream) {
    const float* feats   = (const float*)d_in[0];
    const float* trans   = (const float*)d_in[1];
    const int*   tags    = (const int*)d_in[2];
    const int*   lengths = (const int*)d_in[3];

    int B = in_sizes[3];
    int T = in_sizes[2] / B;

    init_out_kernel<<<1, 64, 0, stream>>>((float*)d_out);
    crf_fused_kernel<<<B, 256, 0, stream>>>(
        feats, trans, tags, lengths, (float*)d_out, B, T);
}

// Round 2
// 142.375 us; speedup vs baseline: 1.1050x; 1.0854x over previous
//
#include <hip/hip_runtime.h>

// Fused CRF NLL: B=1024, T=2048, K=9 (START=7, STOP=8).
// One block per sentence, 512 threads = 8 waves = 64 chunk-groups x 8 lanes.
// Phase 1: gold score, data-parallel (4 t-steps/thread), per-wave reduce.
// Phase 2: per-chunk 7x7 linear-space transfer matrix, 1 lane per column.
//   - dynamic chunk length Lb = ceil((len-1)/64): max 32 serial steps
//     (was 64) -- the kernel duration is the longest block's makespan.
//   - E in SGPRs (readfirstlane); lane l loads only f[t][l], shares exp(f)
//     via ds_bpermute; 4-step groups with ef broadcasts hoisted; renorm /4.
// Phase 3a: per-wave segment fold -- wave w log-matmul-folds its own 8 chunk
//   matrices (lane(j,i) holds A[j][i]; 7 bpermutes/step for A's column,
//   LDS float4 reads for Mc's row) in 7 steps. Critical fold span 64 -> 15.
// Phase 3b: threads 0..7 fold the 8 segment matrices with replicated alpha
//   (in-lane lse + 7 shfl redistribute), STOP readout, atomicAdd((fwd-g)/B).

#define START_TAG 7
#define STOP_TAG  8
#define KDIM      9
#define NS        7
#define CHUNKS    64
#define NEGINF    (-1e30f)

__device__ __forceinline__ float rfl(float x) {
    return __int_as_float(__builtin_amdgcn_readfirstlane(__float_as_int(x)));
}

__global__ __launch_bounds__(512, 4) void crf_fused_kernel(
    const float* __restrict__ feats,
    const float* __restrict__ trans,
    const int*   __restrict__ tags,
    const int*   __restrict__ lengths,
    float* __restrict__ out,
    int B, int T)
{
    __shared__ float s_trans[81];
    __shared__ float s_E[49];
    __shared__ float s_M[CHUNKS * 64];   // [c][j*8 + i] rows padded to 8
    __shared__ float s_gold[8];

    const int tid = threadIdx.x;
    const int b   = blockIdx.x;

    if (tid < 81) s_trans[tid] = trans[tid];
    if (tid >= 128 && tid < 177) {
        int k = tid - 128;
        s_E[k] = __expf(trans[(k / 7) * 9 + (k % 7)]);
    }
    __syncthreads();

    const int    len   = lengths[b];
    const int*   tg    = tags  + (size_t)b * T;
    const float* fbase = feats + (size_t)b * T * KDIM;
    // dynamic chunk length over timesteps [1, len)
    const int    Lb    = (len > 1) ? ((len - 1 + CHUNKS - 1) / CHUNKS) : 1;

    // ---------------- phase 1: gold score ----------------
    {
        int per = T >> 9; if (per < 1) per = 1;   // 4 for T=2048
        int t0  = tid * per;
        float g = 0.f;
        if (t0 < len) {
            int te   = min(t0 + per, len);
            int prev = (t0 == 0) ? START_TAG : tg[t0 - 1];
            if (per == 4) {
                #pragma unroll
                for (int k = 0; k < 4; ++k) {
                    int t   = t0 + k;
                    int tc  = min(t, te - 1);
                    int cur = tg[tc];
                    float v = s_trans[cur * 9 + prev] + fbase[(size_t)tc * KDIM + cur];
                    g += (t < te) ? v : 0.f;
                    prev = cur;
                }
            } else {
                for (int k = 0; k < per; ++k) {
                    int t   = t0 + k;
                    int tc  = min(t, te - 1);
                    int cur = tg[tc];
                    float v = s_trans[cur * 9 + prev] + fbase[(size_t)tc * KDIM + cur];
                    g += (t < te) ? v : 0.f;
                    prev = cur;
                }
            }
            if (len - 1 >= t0 && len - 1 < t0 + per)
                g += s_trans[STOP_TAG * 9 + tg[len - 1]];
        }
        #pragma unroll
        for (int off = 32; off > 0; off >>= 1) g += __shfl_xor(g, off, 64);
        if ((tid & 63) == 0) s_gold[tid >> 6] = g;
    }

    // ---------------- phase 2: chunk matrices ----------------
    {
        const int lane8  = tid & 7;
        const int c      = tid >> 3;             // 0..63
        const int tstart = 1 + c * Lb;
        const int tend   = min(tstart + Lb, len);

        if (lane8 < NS) {
            float* Mw = s_M + c * 64;
            if (tstart < tend) {
                float E[49];
                #pragma unroll
                for (int k = 0; k < 49; ++k) E[k] = rfl(s_E[k]);

                // bpermute byte addresses: group base within wave | j
                int baddr[NS];
                #pragma unroll
                for (int j = 0; j < NS; ++j) baddr[j] = (((tid & 56) | j) << 2);

                float p[NS];
                #pragma unroll
                for (int j = 0; j < NS; ++j) p[j] = (j == lane8) ? 1.f : 0.f;
                float s = 0.f;
                int rem = tend - tstart;

                const float* fp = fbase + (size_t)tstart * KDIM + lane8;

                #define CRF_MAT(EF) do {                                        \
                    float q[NS];                                                \
                    _Pragma("unroll")                                           \
                    for (int j = 0; j < NS; ++j) {                              \
                        float acc = E[j * 7] * p[0];                            \
                        _Pragma("unroll")                                       \
                        for (int i = 1; i < NS; ++i)                            \
                            acc = fmaf(E[j * 7 + i], p[i], acc);                \
                        q[j] = acc;                                             \
                    }                                                           \
                    _Pragma("unroll")                                           \
                    for (int j = 0; j < NS; ++j) p[j] = q[j] * EF[j];           \
                } while (0)

                #define CRF_BCAST(DST, XF) do {                                 \
                    float _e = __expf(XF);                                      \
                    _Pragma("unroll")                                           \
                    for (int j = 0; j < NS; ++j)                                \
                        DST[j] = __int_as_float(                                \
                            __builtin_amdgcn_ds_bpermute(                       \
                                baddr[j], __float_as_int(_e)));                 \
                } while (0)

                #define CRF_STEP(XF) do {                                       \
                    float _ef[NS];                                              \
                    CRF_BCAST(_ef, XF);                                         \
                    CRF_MAT(_ef);                                               \
                } while (0)

                #define CRF_RENORM() do {                                       \
                    float m = p[0];                                             \
                    _Pragma("unroll")                                           \
                    for (int j = 1; j < NS; ++j) m = fmaxf(m, p[j]);            \
                    float rm = __builtin_amdgcn_rcpf(m);                        \
                    _Pragma("unroll")                                           \
                    for (int j = 0; j < NS; ++j) p[j] *= rm;                    \
                    s += __logf(m);                                             \
                } while (0)

                // initial preload (clamped so short chunks never read OOB)
                int o1 = KDIM * min(1, rem - 1);
                int o2 = KDIM * min(2, rem - 1);
                int o3 = KDIM * min(3, rem - 1);
                float x0 = fp[0], x1 = fp[o1], x2 = fp[o2], x3 = fp[o3];
                fp += 4 * KDIM;

                while (rem >= 8) {
                    float y0 = fp[0], y1 = fp[KDIM], y2 = fp[2 * KDIM], y3 = fp[3 * KDIM];
                    fp += 4 * KDIM;
                    float efA[NS], efB[NS], efC[NS], efD[NS];
                    CRF_BCAST(efA, x0);
                    CRF_BCAST(efB, x1);
                    CRF_BCAST(efC, x2);
                    CRF_BCAST(efD, x3);
                    CRF_MAT(efA); CRF_MAT(efB); CRF_MAT(efC); CRF_MAT(efD);
                    CRF_RENORM();
                    x0 = y0; x1 = y1; x2 = y2; x3 = y3;
                    rem -= 4;
                }
                if (rem > 4) {
                    int e1 = KDIM * min(1, rem - 5);
                    int e2 = KDIM * min(2, rem - 5);
                    float y0 = fp[0], y1 = fp[e1], y2 = fp[e2];
                    float efA[NS], efB[NS], efC[NS], efD[NS];
                    CRF_BCAST(efA, x0);
                    CRF_BCAST(efB, x1);
                    CRF_BCAST(efC, x2);
                    CRF_BCAST(efD, x3);
                    CRF_MAT(efA); CRF_MAT(efB); CRF_MAT(efC); CRF_MAT(efD);
                    CRF_RENORM();
                    x0 = y0; x1 = y1; x2 = y2;
                    rem -= 4;
                }
                // rem in [1,4]
                CRF_STEP(x0);
                if (rem > 1) CRF_STEP(x1);
                if (rem > 2) CRF_STEP(x2);
                if (rem > 3) CRF_STEP(x3);

                #pragma unroll
                for (int j = 0; j < NS; ++j)
                    Mw[j * 8 + lane8] = __logf(p[j]) + s;

                #undef CRF_MAT
                #undef CRF_BCAST
                #undef CRF_STEP
                #undef CRF_RENORM
            } else {
                #pragma unroll
                for (int j = 0; j < NS; ++j)
                    Mw[j * 8 + lane8] = (j == lane8) ? 0.f : NEGINF;
            }
        }
    }
    __syncthreads();

    // ------- phase 3a: per-wave segment fold (8 chunk mats -> 1 per wave) ----
    // wave w folds chunks 8w..8w+7 (exactly the ones its own lanes built).
    // lane l = j*8+i holds A[j][i]; active lanes j<7 && i<7.
    {
        const int l = tid & 63;
        const int w = tid >> 6;
        const int i = l & 7;
        float* seg = s_M + w * 512;          // 8 chunks x 64 floats

        float A = seg[l];                     // A = M_{8w}
        int baddr[NS];
        #pragma unroll
        for (int k = 0; k < NS; ++k) baddr[k] = ((k << 3) | i) << 2;

        #pragma unroll
        for (int c = 1; c < 8; ++c) {
            const float* Mr = seg + c * 64 + (l & 56);   // row j of Mc
            float4 r0 = *(const float4*)(Mr);
            float4 r1 = *(const float4*)(Mr + 4);
            float ac[NS];
            #pragma unroll
            for (int k = 0; k < NS; ++k)
                ac[k] = __int_as_float(__builtin_amdgcn_ds_bpermute(
                            baddr[k], __float_as_int(A)));
            float t0 = r0.x + ac[0], t1 = r0.y + ac[1], t2 = r0.z + ac[2];
            float t3 = r0.w + ac[3], t4 = r1.x + ac[4], t5 = r1.y + ac[5];
            float t6 = r1.z + ac[6];
            float tm = fmaxf(fmaxf(fmaxf(t0, t1), fmaxf(t2, t3)),
                             fmaxf(fmaxf(t4, t5), t6));
            float sum = ((__expf(t0 - tm) + __expf(t1 - tm)) +
                         (__expf(t2 - tm) + __expf(t3 - tm))) +
                        ((__expf(t4 - tm) + __expf(t5 - tm)) + __expf(t6 - tm));
            A = tm + __logf(sum);
        }
        seg[l] = A;   // segment matrix at s_M[w*512 .. +63]; junk rows/cols
                      // (j==7 / i==7) land in never-read padding slots.
    }
    __syncthreads();

    // ------- phase 3b: fold 8 segment matrices with replicated alpha --------
    if (tid < 8) {
        const int  lane  = tid;
        const bool isrow = (lane < NS);
        const int  row   = isrow ? lane : 0;

        // every lane holds the full alpha vector (t=0 emission applied)
        float a[NS];
        #pragma unroll
        for (int i = 0; i < NS; ++i)
            a[i] = s_trans[i * 9 + START_TAG] + fbase[i];
        float S;
        {
            float mm = fmaxf(fmaxf(fmaxf(a[0], a[1]), fmaxf(a[2], a[3])),
                             fmaxf(fmaxf(a[4], a[5]), a[6]));
            S = mm;
            #pragma unroll
            for (int i = 0; i < NS; ++i) a[i] -= mm;
        }

        const float* Mr0 = s_M + row * 8;
        float4 mA = *(const float4*)(Mr0);
        float4 mB = *(const float4*)(Mr0 + 4);
        #pragma unroll
        for (int w = 0; w < 8; ++w) {
            int wn = min(w + 1, 7);
            float4 nA = *(const float4*)(Mr0 + wn * 512);
            float4 nB = *(const float4*)(Mr0 + wn * 512 + 4);
            float t0 = mA.x + a[0], t1 = mA.y + a[1], t2 = mA.z + a[2];
            float t3 = mA.w + a[3], t4 = mB.x + a[4], t5 = mB.y + a[5];
            float t6 = mB.z + a[6];
            float tm = fmaxf(fmaxf(fmaxf(t0, t1), fmaxf(t2, t3)),
                             fmaxf(fmaxf(t4, t5), t6));
            float e0 = __expf(t0 - tm), e1 = __expf(t1 - tm), e2 = __expf(t2 - tm);
            float e3 = __expf(t3 - tm), e4 = __expf(t4 - tm), e5 = __expf(t5 - tm);
            float e6 = __expf(t6 - tm);
            float sum = ((e0 + e1) + (e2 + e3)) + ((e4 + e5) + e6);
            float na = isrow ? (tm + __logf(sum)) : NEGINF;
            // redistribute new alpha to all lanes, recenter in-lane
            float b0 = __shfl(na, 0, 8), b1 = __shfl(na, 1, 8), b2 = __shfl(na, 2, 8);
            float b3 = __shfl(na, 3, 8), b4 = __shfl(na, 4, 8), b5 = __shfl(na, 5, 8);
            float b6 = __shfl(na, 6, 8);
            float mm = fmaxf(fmaxf(fmaxf(b0, b1), fmaxf(b2, b3)),
                             fmaxf(fmaxf(b4, b5), b6));
            a[0] = b0 - mm; a[1] = b1 - mm; a[2] = b2 - mm;
            a[3] = b3 - mm; a[4] = b4 - mm; a[5] = b5 - mm;
            a[6] = b6 - mm;
            S += mm;
            mA = nA; mB = nB;
        }

        if (lane == 0) {
            float t0 = a[0] + s_trans[STOP_TAG * 9 + 0];
            float t1 = a[1] + s_trans[STOP_TAG * 9 + 1];
            float t2 = a[2] + s_trans[STOP_TAG * 9 + 2];
            float t3 = a[3] + s_trans[STOP_TAG * 9 + 3];
            float t4 = a[4] + s_trans[STOP_TAG * 9 + 4];
            float t5 = a[5] + s_trans[STOP_TAG * 9 + 5];
            float t6 = a[6] + s_trans[STOP_TAG * 9 + 6];
            float tm = fmaxf(fmaxf(fmaxf(t0, t1), fmaxf(t2, t3)),
                             fmaxf(fmaxf(t4, t5), t6));
            float sum = ((__expf(t0 - tm) + __expf(t1 - tm)) +
                         (__expf(t2 - tm) + __expf(t3 - tm))) +
                        ((__expf(t4 - tm) + __expf(t5 - tm)) + __expf(t6 - tm));
            float fwd = S + tm + __logf(sum);
            float g = (s_gold[0] + s_gold[1] + s_gold[2] + s_gold[3]) +
                      (s_gold[4] + s_gold[5] + s_gold[6] + s_gold[7]);
            atomicAdd(out, (fwd - g) * (1.0f / (float)B));
        }
    }
}

__global__ void init_out_kernel(float* out) {
    if (threadIdx.x == 0) out[0] = 0.f;
}

extern "C" void kernel_launch(void* const* d_in, const int* in_sizes, int n_in,
                              void* d_out, int out_size, void* d_ws, size_t ws_size,
                              hipStream_t stream) {
    const float* feats   = (const float*)d_in[0];
    const float* trans   = (const float*)d_in[1];
    const int*   tags    = (const int*)d_in[2];
    const int*   lengths = (const int*)d_in[3];

    int B = in_sizes[3];
    int T = in_sizes[2] / B;

    init_out_kernel<<<1, 64, 0, stream>>>((float*)d_out);
    crf_fused_kernel<<<B, 512, 0, stream>>>(
        feats, trans, tags, lengths, (float*)d_out, B, T);
}